// Round 7
// baseline (131.180 us; speedup 1.0000x reference)
//
#include <hip/hip_runtime.h>

#define NSET 48
#define NITEM 128
#define DIM 256
#define HEADS 4
#define NROWS (NSET * NITEM)   // 6144 rows per source

typedef _Float16 f16;
typedef _Float16 f16x8 __attribute__((ext_vector_type(8)));
typedef _Float16 f16x4 __attribute__((ext_vector_type(4)));
typedef float    f32x4 __attribute__((ext_vector_type(4)));

// ---- fragment-major layout ----
// A source matrix is stored per 128-row "set" (32768 halves = 64KB). Within a
// set: 64 chunks of 512 halves (1KB), chunk = (r/16)*8 + (k/32). Within a
// chunk, lane-slot l (16B) holds row r = rbase+(l&15), halves kbase+(l>>4)*8..+8
// -- exactly the mfma_16x16x32 A/B fragment for that (row-block, k-block).
// So an operand fragment load is ONE lane-contiguous 1KB wave-load instead of
// 16 scattered 64B segments (the R5 L1-transaction bottleneck).
#define SETH 32768   // halves per set
__device__ __forceinline__ int faddr(int r, int k) {   // in halves, within a set
  return ((r >> 4) * 8 + (k >> 5)) * 512 + ((((k >> 3) & 3) * 16 + (r & 15)) * 8) + (k & 7);
}

// ---- XCD-aware block map (R6 lesson: default round-robin makes every XCD's
// 4MiB L2 hold all 96 sets -> thrash to L3/fabric). Partition ys into 8
// stripes of 6: per-XCD working set = 6 y-sets + 48 x-sets = 3.4MB < 4MiB.
__device__ __forceinline__ void xcd_map(int bid, int& ys, int& xs) {
  int xcd = bid & 7, t = bid >> 3;     // blocks dispatch round-robin over XCDs
  ys = xcd * 6 + t / NSET;
  xs = t % NSET;
}

// ---- workspace layout (bytes) ----
static constexpr size_t OFF_XYH = 6291456;
static constexpr size_t OFF_WT  = 12582912;
static constexpr size_t OFF_LXY = 12713984;

// ---------------- prep: W transpose + fp16, frag-major ----------------
__global__ __launch_bounds__(256) void k_wt(const float* __restrict__ W,
                                            f16* __restrict__ WT_F) {
  int d = blockIdx.x, c = threadIdx.x;
  WT_F[(c >> 7) * SETH + faddr(c & 127, d)] = (f16)W[d * DIM + c];
}

// ---------------- prep: row l2-normalize + fp16 casts, frag-major ----------------
__global__ __launch_bounds__(256) void k_norm(const float* __restrict__ x,
                                              const float* __restrict__ y,
                                              f16* __restrict__ XYN_F,
                                              f16* __restrict__ XYH_F) {
  int rg   = blockIdx.x * 4 + (threadIdx.x >> 6);   // global row 0..12287
  int lane = threadIdx.x & 63;
  const float* src = (rg < NROWS) ? (x + (size_t)rg * DIM)
                                  : (y + (size_t)(rg - NROWS) * DIM);
  float4 v = *(const float4*)(src + lane * 4);
  float ss = v.x * v.x + v.y * v.y + v.z * v.z + v.w * v.w;
  #pragma unroll
  for (int off = 32; off >= 1; off >>= 1) ss += __shfl_xor(ss, off);
  float rn = 1.0f / sqrtf(fmaxf(ss, 1e-12f));       // tf.nn.l2_normalize semantics
  f16x4 hn = { (f16)(v.x * rn), (f16)(v.y * rn), (f16)(v.z * rn), (f16)(v.w * rn) };
  f16x4 hr = { (f16)v.x, (f16)v.y, (f16)v.z, (f16)v.w };
  int dst = (rg >> 7) * SETH + faddr(rg & 127, lane * 4);   // 8B slot
  *(f16x4*)(XYN_F + dst) = hn;
  *(f16x4*)(XYH_F + dst) = hr;
}

// ---------------- prep: projection GEMM  LXY[R][c] = XYH[R][:] . WT[c][:] ----------------
__global__ __launch_bounds__(256, 2) void k_proj(const f16* __restrict__ XYH_F,
                                                 const f16* __restrict__ WT_F,
                                                 f16* __restrict__ LXY_F) {
  const int bid = blockIdx.x, rt = bid >> 1, ct = bid & 1;   // 96 row-sets x 2 col-tiles
  const int tid = threadIdx.x, w = tid >> 6, lane = tid & 63;
  const int wR = (w >> 1) * 64;        // R range within set
  const int wC = (w & 1) * 64;         // c range within 128-col tile
  const int la = lane & 15, lb = lane >> 4;

  const f16* pa[4];                    // A = WT rows (c), set ct
  const f16* pb[4];                    // B = XYH rows (R), set rt
  #pragma unroll
  for (int m = 0; m < 4; ++m)
    pa[m] = WT_F + ct * SETH + ((wC >> 4) + m) * 4096 + lane * 8;
  #pragma unroll
  for (int n = 0; n < 4; ++n)
    pb[n] = XYH_F + rt * SETH + ((wR >> 4) + n) * 4096 + lane * 8;

  f32x4 acc[4][4] = {};
  #pragma unroll
  for (int k0 = 0; k0 < DIM; k0 += 32) {
    const int ko = (k0 >> 5) * 512;
    f16x8 a[4], b[4];
    #pragma unroll
    for (int m = 0; m < 4; ++m) a[m] = *(const f16x8*)(pa[m] + ko);
    #pragma unroll
    for (int n = 0; n < 4; ++n) b[n] = *(const f16x8*)(pb[n] + ko);
    #pragma unroll
    for (int m = 0; m < 4; ++m)
      #pragma unroll
      for (int n = 0; n < 4; ++n)
        acc[m][n] = __builtin_amdgcn_mfma_f32_16x16x32_f16(a[m], b[n], acc[m][n], 0, 0, 0);
  }
  // D[row=c][col=R]: lane holds 4 consecutive c at fixed R -> 8B frag-major write
  #pragma unroll
  for (int m = 0; m < 4; ++m)
    #pragma unroll
    for (int n = 0; n < 4; ++n) {
      int rloc = wR + n * 16 + la;               // R within set rt
      int c0   = ct * 128 + wC + m * 16 + lb * 4;
      f16x4 hv = { (f16)acc[m][n][0], (f16)acc[m][n][1],
                   (f16)acc[m][n][2], (f16)acc[m][n][3] };
      *(f16x4*)(LXY_F + rt * SETH + faddr(rloc, c0)) = hv;
    }
}

// ---------------- cos_sim kernel: one block per (ys,xs) ----------------
__global__ __launch_bounds__(256, 2) void k_cos(const f16* __restrict__ XYN_F,
                                                float* __restrict__ out0) {
  __shared__ float hbuf[64 * 128];     // 32KB: half of the 128x128 f32 tile
  int ys, xs;
  xcd_map(blockIdx.x, ys, xs);
  const int tid = threadIdx.x, w = tid >> 6, lane = tid & 63;
  const int wj = (w >> 1) * 64;        // j (y item) range -> A operand
  const int wi = (w & 1) * 64;         // i (x item) range -> B operand
  const int la = lane & 15, lb = lane >> 4;

  const f16* pa[4];
  const f16* pb[4];
  #pragma unroll
  for (int m = 0; m < 4; ++m)
    pa[m] = XYN_F + (48 + ys) * SETH + ((wj >> 4) + m) * 4096 + lane * 8;
  #pragma unroll
  for (int n = 0; n < 4; ++n)
    pb[n] = XYN_F + xs * SETH + ((wi >> 4) + n) * 4096 + lane * 8;

  f32x4 acc[4][4] = {};
  #pragma unroll
  for (int k0 = 0; k0 < DIM; k0 += 32) {
    const int ko = (k0 >> 5) * 512;
    f16x8 a[4], b[4];
    #pragma unroll
    for (int m = 0; m < 4; ++m) a[m] = *(const f16x8*)(pa[m] + ko);
    #pragma unroll
    for (int n = 0; n < 4; ++n) b[n] = *(const f16x8*)(pb[n] + ko);
    #pragma unroll
    for (int m = 0; m < 4; ++m)
      #pragma unroll
      for (int n = 0; n < 4; ++n)
        acc[m][n] = __builtin_amdgcn_mfma_f32_16x16x32_f16(a[m], b[n], acc[m][n], 0, 0, 0);
  }

  // epilogue: per 64-row half, LDS-transpose then stream full 512B rows out
  float* base = out0 + (size_t)(ys * NSET + xs) * NITEM * NITEM;
  #pragma unroll
  for (int half = 0; half < 2; ++half) {
    if ((w & 1) == half) {             // waves owning i-range [half*64, half*64+64)
      #pragma unroll
      for (int m = 0; m < 4; ++m)
        #pragma unroll
        for (int n = 0; n < 4; ++n) {
          int il = n * 16 + la;                     // local i: 0..63
          int jb = (wj + m * 16 + lb * 4) * 4;      // byte offset along j
          *(f32x4*)((char*)hbuf + il * 512 + (jb ^ ((il & 15) << 4))) = acc[m][n];
        }
    }
    __syncthreads();
    #pragma unroll
    for (int c = 0; c < 8; ++c) {      // each wave streams 16 rows, 2 rows/instr
      int il = w * 16 + c * 2 + (lane >> 5);
      int jb = (lane & 31) * 16;
      f32x4 v = *(const f32x4*)((char*)hbuf + il * 512 + (jb ^ ((il & 15) << 4)));
      __builtin_nontemporal_store(v, (f32x4*)(base + (size_t)(half * 64 + il) * NITEM) + (lane & 31));
    }
    __syncthreads();
  }
}

// ---------------- score kernel: one block per (ys,xs) ----------------
__global__ __launch_bounds__(256, 2) void k_score(const f16* __restrict__ LXY_F,
                                                  const float* __restrict__ nItem,
                                                  const float* __restrict__ w2,
                                                  float* __restrict__ out1) {
  __shared__ float red[4][4];
  int ys, xs;
  xcd_map(blockIdx.x, ys, xs);
  const int tid = threadIdx.x, w = tid >> 6, lane = tid & 63;
  const int wj = (w >> 1) * 64;        // j (y item) range -> A operand
  const int wi = (w & 1) * 64;         // i (x item) range -> B operand

  const f16* pa[4];
  const f16* pb[4];
  #pragma unroll
  for (int m = 0; m < 4; ++m)
    pa[m] = LXY_F + (48 + ys) * SETH + ((wj >> 4) + m) * 4096 + lane * 8;
  #pragma unroll
  for (int n = 0; n < 4; ++n)
    pb[n] = LXY_F + xs * SETH + ((wi >> 4) + n) * 4096 + lane * 8;

  float rsum[HEADS];
  #pragma unroll
  for (int h = 0; h < HEADS; ++h) {
    f32x4 acc[4][4] = {};
    #pragma unroll
    for (int kk = 0; kk < 2; ++kk) {             // K=64 per head; relu AFTER full K
      const int ko = ((h * 64 + kk * 32) >> 5) * 512;
      f16x8 a[4], b[4];
      #pragma unroll
      for (int m = 0; m < 4; ++m) a[m] = *(const f16x8*)(pa[m] + ko);
      #pragma unroll
      for (int n = 0; n < 4; ++n) b[n] = *(const f16x8*)(pb[n] + ko);
      #pragma unroll
      for (int m = 0; m < 4; ++m)
        #pragma unroll
        for (int n = 0; n < 4; ++n)
          acc[m][n] = __builtin_amdgcn_mfma_f32_16x16x32_f16(a[m], b[n], acc[m][n], 0, 0, 0);
    }
    float s = 0.f;
    #pragma unroll
    for (int m = 0; m < 4; ++m)
      #pragma unroll
      for (int n = 0; n < 4; ++n)
        #pragma unroll
        for (int r = 0; r < 4; ++r) s += fmaxf(acc[m][n][r], 0.f);
    rsum[h] = s;
  }
  #pragma unroll
  for (int off = 32; off >= 1; off >>= 1)
    #pragma unroll
    for (int h = 0; h < HEADS; ++h) rsum[h] += __shfl_xor(rsum[h], off);
  if (lane == 0) {
    #pragma unroll
    for (int h = 0; h < HEADS; ++h) red[w][h] = rsum[h];
  }
  __syncthreads();
  if (tid == 0) {
    // relu(S/8) summed == (sum relu(S))/8 ; then / nItem[x] / nItem[y]; then @ w2
    float inv = 1.0f / (8.0f * nItem[xs] * nItem[ys]);
    float sc = 0.f;
    #pragma unroll
    for (int h = 0; h < HEADS; ++h)
      sc += (red[0][h] + red[1][h] + red[2][h] + red[3][h]) * inv * w2[h];
    out1[ys * NSET + xs] = sc;
  }
}

// ---------------- launch ----------------
extern "C" void kernel_launch(void* const* d_in, const int* in_sizes, int n_in,
                              void* d_out, int out_size, void* d_ws, size_t ws_size,
                              hipStream_t stream) {
  const float* x     = (const float*)d_in[0];
  const float* y     = (const float*)d_in[1];
  const float* nItem = (const float*)d_in[2];
  const float* W     = (const float*)d_in[3];
  const float* w2    = (const float*)d_in[4];
  float* out0 = (float*)d_out;
  float* out1 = out0 + (size_t)NSET * NSET * NITEM * NITEM;

  char* ws = (char*)d_ws;
  f16* XYN_F = (f16*)ws;
  f16* XYH_F = (f16*)(ws + OFF_XYH);
  f16* WT_F  = (f16*)(ws + OFF_WT);
  f16* LXY_F = (f16*)(ws + OFF_LXY);

  k_wt<<<256, 256, 0, stream>>>(W, WT_F);
  k_norm<<<(2 * NROWS) / 4, 256, 0, stream>>>(x, y, XYN_F, XYH_F);
  k_proj<<<192, 256, 0, stream>>>(XYH_F, WT_F, LXY_F);
  k_cos<<<NSET * NSET, 256, 0, stream>>>(XYN_F, out0);
  k_score<<<NSET * NSET, 256, 0, stream>>>(LXY_F, nItem, w2, out1);
}